// Round 1
// baseline (328.657 us; speedup 1.0000x reference)
//
#include <hip/hip_runtime.h>
#include <hip/hip_bf16.h>
#include <stdint.h>

using short8 = __attribute__((ext_vector_type(8))) short;
using f32x4  = __attribute__((ext_vector_type(4))) float;

#define NBITS 3
#define NHEADS 8
#define BATCH 8192
#define DFEAT 512
#define DBASE 1024
#define DHH   1024
#define DOUT  512
#define XCOLS (NBITS + DFEAT)   // 515

static __device__ __forceinline__ unsigned short f2bf(float f) {
    union { float f; unsigned u; } v; v.f = f;
    unsigned r = v.u + 0x7FFFu + ((v.u >> 16) & 1u);   // RNE
    return (unsigned short)(r >> 16);
}

// ---------------- bucket rows by head ----------------
__global__ void k_bucket(const float* __restrict__ x, int* __restrict__ cnt,
                         int* __restrict__ rows) {
    int r = blockIdx.x * 256 + threadIdx.x;
    if (r >= BATCH) return;
    const float* xr = x + (size_t)r * XCOLS;
    int h = (xr[0] > 0.5f ? 1 : 0) | (xr[1] > 0.5f ? 2 : 0) | (xr[2] > 0.5f ? 4 : 0);
    int slot = atomicAdd(cnt + h, 1);
    rows[h * BATCH + slot] = r;
}

// ---------------- feat fp32 -> bf16 [8192][512] ----------------
__global__ void k_feat(const float* __restrict__ x, unsigned short* __restrict__ feat) {
    int t = blockIdx.x * 256 + threadIdx.x;          // 8192*64 threads
    int row = t >> 6, c8 = (t & 63) << 3;
    const float* src = x + (size_t)row * XCOLS + NBITS + c8;
    short8 v;
#pragma unroll
    for (int i = 0; i < 8; ++i) v[i] = (short)f2bf(src[i]);
    *(short8*)(feat + (size_t)row * DFEAT + c8) = v;
}

// ---------------- W[b][K][N] fp32 -> WT[b][N][K] bf16 (transpose+convert) ----------------
__global__ void k_transpose(const float* __restrict__ W, unsigned short* __restrict__ WT,
                            int K, int N) {
    __shared__ float tile[32][33];
    int b  = blockIdx.z;
    int n0 = blockIdx.x << 5, k0 = blockIdx.y << 5;
    int tx = threadIdx.x & 31, ty = threadIdx.x >> 5;     // 32 x 8
    const float* Wb = W + (size_t)b * K * N;
    unsigned short* WTb = WT + (size_t)b * K * N;
#pragma unroll
    for (int j = 0; j < 32; j += 8)
        tile[ty + j][tx] = Wb[(size_t)(k0 + ty + j) * N + n0 + tx];
    __syncthreads();
#pragma unroll
    for (int j = 0; j < 32; j += 8)
        WTb[(size_t)(n0 + ty + j) * K + k0 + tx] = f2bf(tile[tx][ty + j]);
}

// ---------------- 128x128 MFMA GEMM, optional row gather/scatter ----------------
// C[rows][n] = act(A[rows] @ BT[head]^T + bias[head]);  BT is [N][K] row-major.
template<bool GATHER, bool RELU, bool OUTBF16>
__global__ __launch_bounds__(256, 2)
void k_gemm(const unsigned short* __restrict__ A, int lda, int K,
            const unsigned short* __restrict__ BT,
            const float* __restrict__ bias,
            void* __restrict__ C, int ldc,
            const int* __restrict__ rowsAll, const int* __restrict__ cntAll,
            int Nfull) {
    const int head = blockIdx.z;
    const int m0 = blockIdx.x * 128;
    const int n0 = blockIdx.y * 128;
    int M = BATCH;
    const int* rows = nullptr;
    if (GATHER) {
        M = cntAll[head];
        if (m0 >= M) return;
        rows = rowsAll + head * BATCH;
    }
    const unsigned short* BTh = BT + (size_t)head * Nfull * K;
    const float* biash = bias + (size_t)head * Nfull;

    __shared__ __align__(16) unsigned short As[128 * 32];
    __shared__ __align__(16) unsigned short Bs[128 * 32];

    const int t    = threadIdx.x;
    const int wave = t >> 6;
    const int lane = t & 63;
    const int wr = wave >> 1, wc = wave & 1;

    // staging chunk i = p*256 + t covers 8 bf16: A row = i>>2, kchunk = i&3
    const unsigned short* gA[2];
    const unsigned short* gB[2];
#pragma unroll
    for (int p = 0; p < 2; ++p) {
        int i = p * 256 + t;
        int idx = m0 + (i >> 2);
        int r;
        if (GATHER) { if (idx >= M) idx = M - 1; r = rows[idx]; }
        else r = idx;
        gA[p] = A + (size_t)r * lda + (i & 3) * 8;
        int nrow = n0 + (i >> 2);
        gB[p] = BTh + (size_t)nrow * K + (i & 3) * 8;
    }
    char* lAs = (char*)As;
    char* lBs = (char*)Bs;

    f32x4 acc[4][4] = {};
    const int ln = lane & 15, lq = lane >> 4;

    for (int kt = 0; kt < K; kt += 32) {
#pragma unroll
        for (int p = 0; p < 2; ++p) {
            __builtin_amdgcn_global_load_lds(
                (const __attribute__((address_space(1))) void*)(gA[p] + kt),
                (__attribute__((address_space(3))) void*)(lAs + (p * 256 + wave * 64) * 16),
                16, 0, 0);
            __builtin_amdgcn_global_load_lds(
                (const __attribute__((address_space(1))) void*)(gB[p] + kt),
                (__attribute__((address_space(3))) void*)(lBs + (p * 256 + wave * 64) * 16),
                16, 0, 0);
        }
        __syncthreads();
        short8 af[4], bfr[4];
#pragma unroll
        for (int m = 0; m < 4; ++m)
            af[m] = *(const short8*)(As + (wr * 64 + m * 16 + ln) * 32 + lq * 8);
#pragma unroll
        for (int n = 0; n < 4; ++n)
            bfr[n] = *(const short8*)(Bs + (wc * 64 + n * 16 + ln) * 32 + lq * 8);
#pragma unroll
        for (int m = 0; m < 4; ++m)
#pragma unroll
            for (int n = 0; n < 4; ++n)
                acc[m][n] = __builtin_amdgcn_mfma_f32_16x16x32_bf16(af[m], bfr[n], acc[m][n], 0, 0, 0);
        __syncthreads();
    }

    // epilogue: C/D layout col = lane&15, row = (lane>>4)*4 + r
#pragma unroll
    for (int n = 0; n < 4; ++n) {
        int col = n0 + wc * 64 + n * 16 + ln;
        float bv = biash[col];
#pragma unroll
        for (int m = 0; m < 4; ++m) {
#pragma unroll
            for (int r = 0; r < 4; ++r) {
                int lr = wr * 64 + m * 16 + lq * 4 + r;
                int grow;
                if (GATHER) {
                    if (m0 + lr >= M) continue;
                    grow = rows[m0 + lr];
                } else {
                    grow = m0 + lr;
                }
                float v = acc[m][n][r] + bv;
                if (RELU) v = fmaxf(v, 0.0f);
                if (OUTBF16)
                    ((unsigned short*)C)[(size_t)grow * ldc + col] = f2bf(v);
                else
                    ((float*)C)[(size_t)grow * ldc + col] = v;
            }
        }
    }
}

extern "C" void kernel_launch(void* const* d_in, const int* in_sizes, int n_in,
                              void* d_out, int out_size, void* d_ws, size_t ws_size,
                              hipStream_t stream) {
    const float* x   = (const float*)d_in[0];
    const float* Wb  = (const float*)d_in[1];
    const float* bb  = (const float*)d_in[2];
    const float* Wh1 = (const float*)d_in[3];
    const float* bh1 = (const float*)d_in[4];
    const float* Wh2 = (const float*)d_in[5];
    const float* bh2 = (const float*)d_in[6];

    char* ws = (char*)d_ws;
    unsigned short* feat = (unsigned short*)(ws);                          //  8 MB
    unsigned short* WbT  = (unsigned short*)(ws + (8ull  << 20));          //  1 MB
    unsigned short* Wh1T = (unsigned short*)(ws + (9ull  << 20));          // 16 MB
    unsigned short* Wh2T = (unsigned short*)(ws + (25ull << 20));          //  8 MB
    unsigned short* base = (unsigned short*)(ws + (33ull << 20));          // 16 MB
    unsigned short* hbuf = (unsigned short*)(ws + (49ull << 20));          // 16 MB
    int* rows            = (int*)(ws + (65ull << 20));                     // 256 KB
    int* cnt             = (int*)(ws + (65ull << 20) + (256ull << 10));    // 32 B

    hipMemsetAsync(cnt, 0, NHEADS * sizeof(int), stream);
    k_bucket<<<BATCH / 256, 256, 0, stream>>>(x, cnt, rows);
    k_feat<<<(BATCH * 64) / 256, 256, 0, stream>>>(x, feat);
    k_transpose<<<dim3(DBASE / 32, DFEAT / 32, 1), 256, 0, stream>>>(Wb, WbT, DFEAT, DBASE);
    k_transpose<<<dim3(DHH / 32, DBASE / 32, NHEADS), 256, 0, stream>>>(Wh1, Wh1T, DBASE, DHH);
    k_transpose<<<dim3(DOUT / 32, DHH / 32, NHEADS), 256, 0, stream>>>(Wh2, Wh2T, DHH, DOUT);

    // GEMM1: base = relu(feat @ Wb + bb)            M=8192 K=512  N=1024
    k_gemm<false, true, true><<<dim3(64, DBASE / 128, 1), 256, 0, stream>>>(
        feat, DFEAT, DFEAT, WbT, bb, base, DBASE, nullptr, nullptr, DBASE);
    // GEMM2: h = relu(base @ Wh1[head] + bh1[head]) grouped, K=1024 N=1024
    k_gemm<true, true, true><<<dim3(64, DHH / 128, NHEADS), 256, 0, stream>>>(
        base, DBASE, DBASE, Wh1T, bh1, hbuf, DHH, rows, cnt, DHH);
    // GEMM3: out = h @ Wh2[head] + bh2[head]        grouped, K=1024 N=512, fp32 out
    k_gemm<true, false, false><<<dim3(64, DOUT / 128, NHEADS), 256, 0, stream>>>(
        hbuf, DHH, DHH, Wh2T, bh2, d_out, DOUT, rows, cnt, DOUT);
}

// Round 2
// 327.038 us; speedup vs baseline: 1.0049x; 1.0049x over previous
//
#include <hip/hip_runtime.h>
#include <hip/hip_bf16.h>
#include <stdint.h>

using short8 = __attribute__((ext_vector_type(8))) short;
using f32x4  = __attribute__((ext_vector_type(4))) float;

#define NBITS 3
#define NHEADS 8
#define BATCH 8192
#define DFEAT 512
#define DBASE 1024
#define DHH   1024
#define DOUT  512
#define XCOLS (NBITS + DFEAT)   // 515

static __device__ __forceinline__ unsigned short f2bf(float f) {
    union { float f; unsigned u; } v; v.f = f;
    unsigned r = v.u + 0x7FFFu + ((v.u >> 16) & 1u);   // RNE
    return (unsigned short)(r >> 16);
}

// ---------------- bucket rows by head ----------------
__global__ void k_bucket(const float* __restrict__ x, int* __restrict__ cnt,
                         int* __restrict__ rows) {
    int r = blockIdx.x * 256 + threadIdx.x;
    if (r >= BATCH) return;
    const float* xr = x + (size_t)r * XCOLS;
    int h = (xr[0] > 0.5f ? 1 : 0) | (xr[1] > 0.5f ? 2 : 0) | (xr[2] > 0.5f ? 4 : 0);
    int slot = atomicAdd(cnt + h, 1);
    rows[h * BATCH + slot] = r;
}

// ---------------- feat fp32 -> bf16 [8192][512] ----------------
__global__ void k_feat(const float* __restrict__ x, unsigned short* __restrict__ feat) {
    int t = blockIdx.x * 256 + threadIdx.x;          // 8192*64 threads
    int row = t >> 6, c8 = (t & 63) << 3;
    const float* src = x + (size_t)row * XCOLS + NBITS + c8;
    short8 v;
#pragma unroll
    for (int i = 0; i < 8; ++i) v[i] = (short)f2bf(src[i]);
    *(short8*)(feat + (size_t)row * DFEAT + c8) = v;
}

// ---------------- W[b][K][N] fp32 -> WT[b][N][K] bf16 (transpose+convert) ----------------
__global__ void k_transpose(const float* __restrict__ W, unsigned short* __restrict__ WT,
                            int K, int N) {
    __shared__ float tile[32][33];
    int b  = blockIdx.z;
    int n0 = blockIdx.x << 5, k0 = blockIdx.y << 5;
    int tx = threadIdx.x & 31, ty = threadIdx.x >> 5;     // 32 x 8
    const float* Wb = W + (size_t)b * K * N;
    unsigned short* WTb = WT + (size_t)b * K * N;
#pragma unroll
    for (int j = 0; j < 32; j += 8)
        tile[ty + j][tx] = Wb[(size_t)(k0 + ty + j) * N + n0 + tx];
    __syncthreads();
#pragma unroll
    for (int j = 0; j < 32; j += 8)
        WTb[(size_t)(n0 + ty + j) * K + k0 + tx] = f2bf(tile[tx][ty + j]);
}

// ---------------- 128x128 MFMA GEMM, 2-phase pipelined, optional gather ----------------
// C[rows][n] = act(A[rows] @ BT[head]^T + bias[head]);  BT is [N][K] row-major.
template<bool GATHER, bool RELU, bool OUTBF16>
__global__ __launch_bounds__(256, 2)
void k_gemm(const unsigned short* __restrict__ A, int lda, int K,
            const unsigned short* __restrict__ BT,
            const float* __restrict__ bias,
            void* __restrict__ C, int ldc,
            const int* __restrict__ rowsAll, const int* __restrict__ cntAll,
            int Nfull) {
    const int head = blockIdx.z;
    const int m0 = blockIdx.x * 128;
    const int n0 = blockIdx.y * 128;
    int M = BATCH;
    const int* rows = nullptr;
    if (GATHER) {
        M = cntAll[head];
        if (m0 >= M) return;
        rows = rowsAll + head * BATCH;
    }
    const unsigned short* BTh = BT + (size_t)head * Nfull * K;
    const float* biash = bias + (size_t)head * Nfull;

    // double-buffered: 2 x (8KB A + 8KB B) = 32 KB
    __shared__ __align__(16) unsigned short As[2][128 * 32];
    __shared__ __align__(16) unsigned short Bs[2][128 * 32];

    const int t    = threadIdx.x;
    const int wave = t >> 6;
    const int lane = t & 63;
    const int wr = wave >> 1, wc = wave & 1;

    // staging chunk i = p*256 + t covers 8 bf16: row = i>>2, kchunk = i&3
    const unsigned short* gA[2];
    const unsigned short* gB[2];
#pragma unroll
    for (int p = 0; p < 2; ++p) {
        int i = p * 256 + t;
        int idx = m0 + (i >> 2);
        int r;
        if (GATHER) { if (idx >= M) idx = M - 1; r = rows[idx]; }
        else r = idx;
        gA[p] = A + (size_t)r * lda + (i & 3) * 8;
        int nrow = n0 + (i >> 2);
        gB[p] = BTh + (size_t)nrow * K + (i & 3) * 8;
    }
    char* lAs = (char*)As;
    char* lBs = (char*)Bs;
    const int dstOff = (wave * 64) * 16;   // wave-uniform base; lane offset applied by HW

#define STAGE(koff, buf)                                                              \
    {                                                                                 \
        _Pragma("unroll")                                                             \
        for (int p = 0; p < 2; ++p) {                                                 \
            __builtin_amdgcn_global_load_lds(                                         \
                (const __attribute__((address_space(1))) void*)(gA[p] + (koff)),      \
                (__attribute__((address_space(3))) void*)(lAs + (buf) * 8192 + p * 4096 + dstOff), \
                16, 0, 0);                                                            \
            __builtin_amdgcn_global_load_lds(                                         \
                (const __attribute__((address_space(1))) void*)(gB[p] + (koff)),      \
                (__attribute__((address_space(3))) void*)(lBs + (buf) * 8192 + p * 4096 + dstOff), \
                16, 0, 0);                                                            \
        }                                                                             \
    }

    f32x4 acc[4][4] = {};
    const int ln = lane & 15, lq = lane >> 4;
    const int nt = K >> 5;

    STAGE(0, 0);
    __syncthreads();                       // drain vmcnt(0) + barrier: buf0 ready

    for (int tk = 0; tk < nt; ++tk) {
        const int cur = tk & 1;
        if (tk + 1 < nt) STAGE((tk + 1) << 5, cur ^ 1);   // prefetch next tile

        short8 af[4], bfr[4];
#pragma unroll
        for (int m = 0; m < 4; ++m)
            af[m] = *(const short8*)(As[cur] + (wr * 64 + m * 16 + ln) * 32 + lq * 8);
#pragma unroll
        for (int n = 0; n < 4; ++n)
            bfr[n] = *(const short8*)(Bs[cur] + (wc * 64 + n * 16 + ln) * 32 + lq * 8);
#pragma unroll
        for (int m = 0; m < 4; ++m)
#pragma unroll
            for (int n = 0; n < 4; ++n)
                acc[m][n] = __builtin_amdgcn_mfma_f32_16x16x32_bf16(af[m], bfr[n], acc[m][n], 0, 0, 0);

        __syncthreads();                   // drain (overlapped with above compute) + barrier
    }
#undef STAGE

    // epilogue: C/D layout col = lane&15, row = (lane>>4)*4 + r
#pragma unroll
    for (int n = 0; n < 4; ++n) {
        int col = n0 + wc * 64 + n * 16 + ln;
        float bv = biash[col];
#pragma unroll
        for (int m = 0; m < 4; ++m) {
#pragma unroll
            for (int r = 0; r < 4; ++r) {
                int lr = wr * 64 + m * 16 + lq * 4 + r;
                int grow;
                if (GATHER) {
                    if (m0 + lr >= M) continue;
                    grow = rows[m0 + lr];
                } else {
                    grow = m0 + lr;
                }
                float v = acc[m][n][r] + bv;
                if (RELU) v = fmaxf(v, 0.0f);
                if (OUTBF16)
                    ((unsigned short*)C)[(size_t)grow * ldc + col] = f2bf(v);
                else
                    ((float*)C)[(size_t)grow * ldc + col] = v;
            }
        }
    }
}

extern "C" void kernel_launch(void* const* d_in, const int* in_sizes, int n_in,
                              void* d_out, int out_size, void* d_ws, size_t ws_size,
                              hipStream_t stream) {
    const float* x   = (const float*)d_in[0];
    const float* Wb  = (const float*)d_in[1];
    const float* bb  = (const float*)d_in[2];
    const float* Wh1 = (const float*)d_in[3];
    const float* bh1 = (const float*)d_in[4];
    const float* Wh2 = (const float*)d_in[5];
    const float* bh2 = (const float*)d_in[6];

    char* ws = (char*)d_ws;
    unsigned short* feat = (unsigned short*)(ws);                          //  8 MB
    unsigned short* WbT  = (unsigned short*)(ws + (8ull  << 20));          //  1 MB
    unsigned short* Wh1T = (unsigned short*)(ws + (9ull  << 20));          // 16 MB
    unsigned short* Wh2T = (unsigned short*)(ws + (25ull << 20));          //  8 MB
    unsigned short* base = (unsigned short*)(ws + (33ull << 20));          // 16 MB
    unsigned short* hbuf = (unsigned short*)(ws + (49ull << 20));          // 16 MB
    int* rows            = (int*)(ws + (65ull << 20));                     // 256 KB
    int* cnt             = (int*)(ws + (65ull << 20) + (256ull << 10));    // 32 B

    hipMemsetAsync(cnt, 0, NHEADS * sizeof(int), stream);
    k_bucket<<<BATCH / 256, 256, 0, stream>>>(x, cnt, rows);
    k_feat<<<(BATCH * 64) / 256, 256, 0, stream>>>(x, feat);
    k_transpose<<<dim3(DBASE / 32, DFEAT / 32, 1), 256, 0, stream>>>(Wb, WbT, DFEAT, DBASE);
    k_transpose<<<dim3(DHH / 32, DBASE / 32, NHEADS), 256, 0, stream>>>(Wh1, Wh1T, DBASE, DHH);
    k_transpose<<<dim3(DOUT / 32, DHH / 32, NHEADS), 256, 0, stream>>>(Wh2, Wh2T, DHH, DOUT);

    // GEMM1: base = relu(feat @ Wb + bb)            M=8192 K=512  N=1024
    k_gemm<false, true, true><<<dim3(64, DBASE / 128, 1), 256, 0, stream>>>(
        feat, DFEAT, DFEAT, WbT, bb, base, DBASE, nullptr, nullptr, DBASE);
    // GEMM2: h = relu(base @ Wh1[head] + bh1[head]) grouped, K=1024 N=1024
    k_gemm<true, true, true><<<dim3(64, DHH / 128, NHEADS), 256, 0, stream>>>(
        base, DBASE, DBASE, Wh1T, bh1, hbuf, DHH, rows, cnt, DHH);
    // GEMM3: out = h @ Wh2[head] + bh2[head]        grouped, K=1024 N=512, fp32 out
    k_gemm<true, false, false><<<dim3(64, DOUT / 128, NHEADS), 256, 0, stream>>>(
        hbuf, DHH, DHH, Wh2T, bh2, d_out, DOUT, rows, cnt, DOUT);
}

// Round 4
// 323.867 us; speedup vs baseline: 1.0148x; 1.0098x over previous
//
#include <hip/hip_runtime.h>
#include <hip/hip_bf16.h>
#include <stdint.h>

using short8 = __attribute__((ext_vector_type(8))) short;
using f32x4  = __attribute__((ext_vector_type(4))) float;

#define NBITS 3
#define NHEADS 8
#define BATCH 8192
#define DFEAT 512
#define DBASE 1024
#define DHH   1024
#define DOUT  512
#define XCOLS (NBITS + DFEAT)   // 515

static __device__ __forceinline__ unsigned short f2bf(float f) {
    union { float f; unsigned u; } v; v.f = f;
    unsigned r = v.u + 0x7FFFu + ((v.u >> 16) & 1u);   // RNE
    return (unsigned short)(r >> 16);
}

// ---------------- bucket rows by head ----------------
__global__ void k_bucket(const float* __restrict__ x, int* __restrict__ cnt,
                         int* __restrict__ rows) {
    int r = blockIdx.x * 256 + threadIdx.x;
    if (r >= BATCH) return;
    const float* xr = x + (size_t)r * XCOLS;
    int h = (xr[0] > 0.5f ? 1 : 0) | (xr[1] > 0.5f ? 2 : 0) | (xr[2] > 0.5f ? 4 : 0);
    int slot = atomicAdd(cnt + h, 1);
    rows[h * BATCH + slot] = r;
}

// ---------------- feat fp32 -> bf16 [8192][512] ----------------
__global__ void k_feat(const float* __restrict__ x, unsigned short* __restrict__ feat) {
    int t = blockIdx.x * 256 + threadIdx.x;
    int row = t >> 6, c8 = (t & 63) << 3;
    const float* src = x + (size_t)row * XCOLS + NBITS + c8;
    short8 v;
#pragma unroll
    for (int i = 0; i < 8; ++i) v[i] = (short)f2bf(src[i]);
    *(short8*)(feat + (size_t)row * DFEAT + c8) = v;
}

// ---------------- W[b][K][N] fp32 -> WT[b][N][K] bf16 ----------------
__global__ void k_transpose(const float* __restrict__ W, unsigned short* __restrict__ WT,
                            int K, int N) {
    __shared__ float tile[32][33];
    int b  = blockIdx.z;
    int n0 = blockIdx.x << 5, k0 = blockIdx.y << 5;
    int tx = threadIdx.x & 31, ty = threadIdx.x >> 5;
    const float* Wb = W + (size_t)b * K * N;
    unsigned short* WTb = WT + (size_t)b * K * N;
#pragma unroll
    for (int j = 0; j < 32; j += 8)
        tile[ty + j][tx] = Wb[(size_t)(k0 + ty + j) * N + n0 + tx];
    __syncthreads();
#pragma unroll
    for (int j = 0; j < 32; j += 8)
        WTb[(size_t)(n0 + ty + j) * K + k0 + tx] = f2bf(tile[tx][ty + j]);
}

// ============ 128x256 MFMA GEMM, 8 waves, BK=64, dbuf LDS, staged-lead pipeline ============
// C[rows][n] = act(A[rows] @ BT[head]^T + bias[head]);  BT is [N][K] row-major.
// LDS: A: 2 dbuf x [128r][64k] bf16 (16KB each) at 0; B: 2 dbuf x [256c][64k] (32KB) at 32768.
// Chunk swizzle: 16B chunk at (row r, phys p) holds logical kchunk p^(r&7)  (involution).
// bid packing: m-tile FASTEST (XCD load balance; head-fastest would pin the big head-0
// workload to one XCD).  mt = bid&63 (64 m-tiles cover 8192 rows; blocks with m0>=M exit).
template<bool GATHER, bool RELU, bool OUTBF16>
__global__ __launch_bounds__(512, 1)
void k_gemm2(const unsigned short* __restrict__ A, int lda, int K,
             const unsigned short* __restrict__ BT,
             const float* __restrict__ bias,
             void* __restrict__ C, int ldc,
             const int* __restrict__ rowsAll, const int* __restrict__ cntAll,
             int Nfull, int nshift) {
    const int bid  = blockIdx.x;
    const int mt   = bid & 63;
    const int nt   = (bid >> 6) & ((1 << nshift) - 1);
    const int head = GATHER ? (bid >> (6 + nshift)) : 0;
    const int m0 = mt * 128;
    const int n0 = nt * 256;
    int M = BATCH;
    const int* rows = nullptr;
    if (GATHER) {
        M = cntAll[head];
        if (m0 >= M) return;
        rows = rowsAll + head * BATCH;
    }
    const unsigned short* BTh = BT + (size_t)head * Nfull * K;
    const float* biash = bias + (size_t)head * Nfull;

    __shared__ __align__(16) char lds[98304];
    char* ldsp = lds;

    const int t    = threadIdx.x;
    const int w    = t >> 6;
    const int lane = t & 63;
    const int wr = w >> 2, wc = w & 3;        // 2 (M) x 4 (N) waves
    const int ln = lane & 15, lq = lane >> 4;

    // ---- staging source pointers (swizzle pre-applied to global k-chunk) ----
    const unsigned short* gA[2];
    {
        int rl  = t >> 3;                      // 0..63 row within half
        int kch = (t & 7) ^ (rl & 7);
#pragma unroll
        for (int h = 0; h < 2; ++h) {
            int idx = m0 + h * 64 + rl;
            int r;
            if (GATHER) { idx = idx < M ? idx : (M - 1); r = rows[idx]; }
            else r = idx;
            gA[h] = A + (size_t)r * lda + kch * 8;
        }
    }
    const unsigned short* gB[2][2];
#pragma unroll
    for (int hb = 0; hb < 2; ++hb)
#pragma unroll
        for (int i = 0; i < 2; ++i) {
            int c   = i * 512 + t;
            int cl  = c >> 3;                  // 0..127 col within half
            int kch = (c & 7) ^ (cl & 7);
            int ncol = n0 + hb * 128 + cl;
            gB[hb][i] = BTh + (size_t)ncol * K + kch * 8;
        }

#define STAGE_A(kt, d)                                                                     \
    { _Pragma("unroll") for (int h = 0; h < 2; ++h)                                        \
        __builtin_amdgcn_global_load_lds(                                                  \
            (const __attribute__((address_space(1))) void*)(gA[h] + (kt) * 64),            \
            (__attribute__((address_space(3))) void*)(ldsp + (d) * 16384 + h * 8192 + w * 1024), \
            16, 0, 0); }
#define STAGE_B(kt, d)                                                                     \
    { _Pragma("unroll") for (int hb = 0; hb < 2; ++hb)                                     \
      _Pragma("unroll") for (int i = 0; i < 2; ++i)                                        \
        __builtin_amdgcn_global_load_lds(                                                  \
            (const __attribute__((address_space(1))) void*)(gB[hb][i] + (kt) * 64),        \
            (__attribute__((address_space(3))) void*)(ldsp + 32768 + (d) * 32768 + hb * 16384 + i * 8192 + w * 1024), \
            16, 0, 0); }
#define LOAD_A(dst, d, ks)                                                                 \
    { _Pragma("unroll") for (int m = 0; m < 4; ++m) {                                      \
        int rA = wr * 64 + m * 16 + ln;                                                    \
        int ch = (((ks) << 2) | lq) ^ (ln & 7);                                            \
        dst[m] = *(const short8*)(ldsp + (d) * 16384 + rA * 128 + ch * 16); } }
#define LOAD_B(dst, d, ks)                                                                 \
    { _Pragma("unroll") for (int n = 0; n < 4; ++n) {                                      \
        int cB = wc * 64 + n * 16 + ln;                                                    \
        int ch = (((ks) << 2) | lq) ^ (ln & 7);                                            \
        dst[n] = *(const short8*)(ldsp + 32768 + (d) * 32768 + cB * 128 + ch * 16); } }
#define MFMA16(av, bv)                                                                     \
    { __builtin_amdgcn_s_setprio(1);                                                       \
      _Pragma("unroll") for (int m = 0; m < 4; ++m)                                        \
      _Pragma("unroll") for (int n = 0; n < 4; ++n)                                        \
        acc[m][n] = __builtin_amdgcn_mfma_f32_16x16x32_bf16(av[m], bv[n], acc[m][n], 0, 0, 0); \
      __builtin_amdgcn_s_setprio(0); }

    f32x4 acc[4][4] = {};
    short8 a0[4], b0[4], a1[4], b1[4];
    const int NT = K >> 6;

    // prologue: tile0 (A+B) -> buf0, tile1 A -> buf1
    STAGE_A(0, 0); STAGE_B(0, 0); STAGE_A(1, 1);
    __syncthreads();
    LOAD_A(a0, 0, 0); LOAD_B(b0, 0, 0);

    for (int kt = 0; kt < NT; ++kt) {
        const int d = kt & 1, o = d ^ 1;
        const int kB = (kt + 1 < NT) ? kt + 1 : NT - 1;
        const int kA = (kt + 2 < NT) ? kt + 2 : NT - 1;
        // P0: stage next tile's B (1-phase lead), read q1 frags, MFMA q0
        STAGE_B(kB, o);
        LOAD_A(a1, d, 1); LOAD_B(b1, d, 1);
        MFMA16(a0, b0);
        // barrier (drains vmcnt): tile kt+1 fully in LDS (A staged 2 phases ago, B 1 phase)
        __syncthreads();
        STAGE_A(kA, d);                      // 2-phase lead for scattered A rows
        LOAD_A(a0, o, 0); LOAD_B(b0, o, 0);  // next tile q0 frags
        MFMA16(a1, b1);
    }
#undef STAGE_A
#undef STAGE_B
#undef LOAD_A
#undef LOAD_B
#undef MFMA16

    // epilogue: C/D layout col = lane&15, row = (lane>>4)*4 + j
#pragma unroll
    for (int n = 0; n < 4; ++n) {
        int col = n0 + wc * 64 + n * 16 + ln;
        float bv = biash[col];
#pragma unroll
        for (int m = 0; m < 4; ++m) {
#pragma unroll
            for (int j = 0; j < 4; ++j) {
                int rt = wr * 64 + m * 16 + lq * 4 + j;
                int grow;
                if (GATHER) {
                    if (m0 + rt >= M) continue;
                    grow = rows[m0 + rt];
                } else {
                    grow = m0 + rt;
                }
                float v = acc[m][n][j] + bv;
                if (RELU) v = fmaxf(v, 0.0f);
                if (OUTBF16)
                    ((unsigned short*)C)[(size_t)grow * ldc + col] = f2bf(v);
                else
                    ((float*)C)[(size_t)grow * ldc + col] = v;
            }
        }
    }
}

extern "C" void kernel_launch(void* const* d_in, const int* in_sizes, int n_in,
                              void* d_out, int out_size, void* d_ws, size_t ws_size,
                              hipStream_t stream) {
    const float* x   = (const float*)d_in[0];
    const float* Wb  = (const float*)d_in[1];
    const float* bb  = (const float*)d_in[2];
    const float* Wh1 = (const float*)d_in[3];
    const float* bh1 = (const float*)d_in[4];
    const float* Wh2 = (const float*)d_in[5];
    const float* bh2 = (const float*)d_in[6];

    char* ws = (char*)d_ws;
    unsigned short* feat = (unsigned short*)(ws);                          //  8 MB
    unsigned short* WbT  = (unsigned short*)(ws + (8ull  << 20));          //  1 MB
    unsigned short* Wh1T = (unsigned short*)(ws + (9ull  << 20));          // 16 MB
    unsigned short* Wh2T = (unsigned short*)(ws + (25ull << 20));          //  8 MB
    unsigned short* base = (unsigned short*)(ws + (33ull << 20));          // 16 MB
    unsigned short* hbuf = (unsigned short*)(ws + (49ull << 20));          // 16 MB
    int* rows            = (int*)(ws + (65ull << 20));                     // 256 KB
    int* cnt             = (int*)(ws + (65ull << 20) + (256ull << 10));    // 32 B

    hipMemsetAsync(cnt, 0, NHEADS * sizeof(int), stream);
    k_bucket<<<BATCH / 256, 256, 0, stream>>>(x, cnt, rows);
    k_feat<<<(BATCH * 64) / 256, 256, 0, stream>>>(x, feat);
    k_transpose<<<dim3(DBASE / 32, DFEAT / 32, 1), 256, 0, stream>>>(Wb, WbT, DFEAT, DBASE);
    k_transpose<<<dim3(DHH / 32, DBASE / 32, NHEADS), 256, 0, stream>>>(Wh1, Wh1T, DBASE, DHH);
    k_transpose<<<dim3(DOUT / 32, DHH / 32, NHEADS), 256, 0, stream>>>(Wh2, Wh2T, DHH, DOUT);

    // GEMM1: base = relu(feat @ Wb + bb)   M=8192 K=512 N=1024 ; 64 mt x 4 nt
    k_gemm2<false, true, true><<<256, 512, 0, stream>>>(
        feat, DFEAT, DFEAT, WbT, bb, base, DBASE, nullptr, nullptr, DBASE, 2);
    // GEMM2: h = relu(base @ Wh1[h] + bh1[h])  grouped, K=1024 N=1024 ; 64 mt x 4 nt x 8 heads
    k_gemm2<true, true, true><<<2048, 512, 0, stream>>>(
        base, DBASE, DBASE, Wh1T, bh1, hbuf, DHH, rows, cnt, DHH, 2);
    // GEMM3: out = h @ Wh2[h] + bh2[h]         grouped, K=1024 N=512, fp32 out ; 64 x 2 x 8
    k_gemm2<true, false, false><<<1024, 512, 0, stream>>>(
        hbuf, DHH, DHH, Wh2T, bh2, d_out, DOUT, rows, cnt, DOUT, 1);
}